// Round 10
// baseline (178.844 us; speedup 1.0000x reference)
//
#include <hip/hip_runtime.h>
#include <stdint.h>

// SDF closest-point + signed distance, 8192 queries x 2048 tris.
//
// Verified correctness model (R4-R9): harness ref = numpy float32 faithful
// chain; strict IEEE f32, NO fma contraction (pragma inside function), numpy
// op order, np.argmin first-occurrence. cp32/write_result/d2approx/margin
// below are byte-identical to the R9 passing kernel.
//
// R10 structure (perf only):
//  - fast records stored COMPONENT-MAJOR in global -> staging writes are
//    lane-contiguous (R9's transposed writes were ~7-way bank conflicts,
//    1.8e7 cycles), staging reads stay coalesced.
//  - ONE LDS pass: per-chunk minima m_c[8] in statically-indexed registers;
//    wave-reduced m1 -> thresh (certified candidate-set margin, R9).
//  - verify re-reads only flagged chunks (any lane's m_c[c] <= thresh)
//    straight from L2 (coalesced component-major), exec-masked exact cp32.

#define RECA 20   // exact record: a,b,c,ab,ac,cb,pad2
#define CHUNK 256 // faces per LDS chunk
#define NCH 8     // chunks per super-chunk (static m_c indexing)
#define SUPER (CHUNK * NCH)
#define SQPB 512  // threads (8 wave-queries per block)

__device__ __forceinline__ float safe32(float x) {
    return (fabsf(x) < 1e-12f) ? 1e-12f : x;
}

// ---- exact path (verified bit-exact vs np-f32 in R4..R9) ----
__device__ __forceinline__ float cp32(
    float px, float py, float pz, const float* __restrict__ t,
    float& rx, float& ry, float& rz)
{
#pragma clang fp contract(off)
    float ax  = t[0],  ay  = t[1],  az  = t[2];
    float bx  = t[3],  by  = t[4],  bz  = t[5];
    float cx  = t[6],  cy  = t[7],  cz  = t[8];
    float abx = t[9],  aby = t[10], abz = t[11];
    float acx = t[12], acy = t[13], acz = t[14];
    float cbx = t[15], cby = t[16], cbz = t[17];

    float apx = px - ax, apy = py - ay, apz = pz - az;
    float bpx = px - bx, bpy = py - by, bpz = pz - bz;
    float qpx = px - cx, qpy = py - cy, qpz = pz - cz;

    float d1 = ((abx * apx) + (aby * apy)) + (abz * apz);
    float d2 = ((acx * apx) + (acy * apy)) + (acz * apz);
    float d3 = ((abx * bpx) + (aby * bpy)) + (abz * bpz);
    float d4 = ((acx * bpx) + (acy * bpy)) + (acz * bpz);
    float d5 = ((abx * qpx) + (aby * qpy)) + (abz * qpz);
    float d6 = ((acx * qpx) + (acy * qpy)) + (acz * qpz);

    float vc = (d1 * d4) - (d3 * d2);
    float vb = (d5 * d2) - (d1 * d6);
    float va = (d3 * d6) - (d5 * d4);
    float e1 = d4 - d3;
    float e2 = d5 - d6;

    bool ca  = (d1 <= 0.0f) && (d2 <= 0.0f);
    bool cb_ = (d3 >= 0.0f) && (d4 <= d3);
    bool cab = (vc <= 0.0f) && (d1 >= 0.0f) && (d3 <= 0.0f);
    bool cc_ = (d6 >= 0.0f) && (d5 <= d6);
    bool cac = (vb <= 0.0f) && (d2 >= 0.0f) && (d6 <= 0.0f);
    bool cbc = (va <= 0.0f) && (e1 >= 0.0f) && (e2 >= 0.0f);

    bool tk  = ca;
    bool m_b  = cb_ && !tk;  tk = tk || cb_;
    bool m_ab = cab && !tk;  tk = tk || cab;
    bool m_c  = cc_ && !tk;  tk = tk || cc_;
    bool m_ac = cac && !tk;  tk = tk || cac;
    bool m_bc = cbc && !tk;  tk = tk || cbc;
    bool m_in = !tk;

    float denom_raw = (va + vb) + vc;
    float num1 = m_ab ? d1 : m_ac ? d2 : m_bc ? e1 : m_in ? vb : 0.0f;
    float den1_raw = m_ab ? (d1 - d3) : m_ac ? (d2 - d6)
                   : m_bc ? (e1 + e2) : m_in ? denom_raw : 1.0f;
    float den1  = safe32(den1_raw);
    float denom = safe32(denom_raw);
    float num2  = m_in ? vc : 0.0f;
    float q1 = num1 / den1;
    float q2 = num2 / denom;

    bool sel_b = m_b || m_bc;
    float basx = m_c ? cx : sel_b ? bx : ax;
    float basy = m_c ? cy : sel_b ? by : ay;
    float basz = m_c ? cz : sel_b ? bz : az;

    bool s_ab = m_ab || m_in;
    float t1x = m_bc ? cbx : m_ac ? acx : s_ab ? abx : 0.0f;
    float t1y = m_bc ? cby : m_ac ? acy : s_ab ? aby : 0.0f;
    float t1z = m_bc ? cbz : m_ac ? acz : s_ab ? abz : 0.0f;

    float t2x = m_in ? acx : 0.0f;
    float t2y = m_in ? acy : 0.0f;
    float t2z = m_in ? acz : 0.0f;

    rx = (basx + (t1x * q1)) + (t2x * q2);
    ry = (basy + (t1y * q1)) + (t2y * q2);
    rz = (basz + (t1z * q1)) + (t2z * q2);

    float dx = px - rx, dy = py - ry, dz = pz - rz;
    return ((dx * dx) + (dy * dy)) + (dz * dz);
}

// Exact epilogue (verified): recompute winner, normal, sign, write.
__device__ __forceinline__ void write_result(
    int q, int widx, const float* __restrict__ trisA,
    float px, float py, float pz, float* __restrict__ out)
{
#pragma clang fp contract(off)
    const float* t = &trisA[(size_t)widx * RECA];
    float rx, ry, rz;
    float best_d2 = cp32(px, py, pz, t, rx, ry, rz);

    float abx = t[9],  aby = t[10], abz = t[11];
    float acx = t[12], acy = t[13], acz = t[14];
    float nx = (aby * acz) - (abz * acy);
    float ny = (abz * acx) - (abx * acz);
    float nz = (abx * acy) - (aby * acx);

    float dx = px - rx, dy = py - ry, dz = pz - rz;
    float sdot = ((dx * nx) + (dy * ny)) + (dz * nz);
    float sgn = (sdot >= 0.0f) ? 1.0f : -1.0f;
    float sdist = sgn * __fsqrt_rn(fmaxf(best_d2, 0.0f));

    out[q * 4 + 0] = rx;
    out[q * 4 + 1] = ry;
    out[q * 4 + 2] = rz;
    out[q * 4 + 3] = sdist;
}

// Fast approximate d2 (two-sided abs error E ~ 7e-5). FMA allowed.
// components: r0=(abx,aby,abz,acx) r1=(acy,acz,aba,abb) r2=(abc,aca,acb,acc)
//             r3=(aa,bb,cc,ax)     r4=(ay,az,nx,ny)     r5=(nz,na,iab,iac)
//             r6=(icb,inn,0,0)
__device__ __forceinline__ float d2approx(
    float px, float py, float pz, float pp,
    float4 r0, float4 r1, float4 r2, float4 r3,
    float4 r4, float4 r5, float4 r6)
{
    float abx = r0.x, aby = r0.y, abz = r0.z, acx = r0.w;
    float acy = r1.x, acz = r1.y, aba = r1.z, abb = r1.w;
    float abc = r2.x, aca = r2.y, acb = r2.z, acc = r2.w;
    float aa = r3.x, bb = r3.y, cc2 = r3.z, ax = r3.w;
    float ay = r4.x, az = r4.y, nx = r4.z, ny = r4.w;
    float nz = r5.x, na = r5.y, iab = r5.z, iac = r5.w;
    float icb = r6.x, inn = r6.y;

    float abp = abx * px + aby * py + abz * pz;
    float acp = acx * px + acy * py + acz * pz;
    float apd = ax * px + ay * py + az * pz;
    float npd = nx * px + ny * py + nz * pz;
    float d1 = abp - aba, d3 = abp - abb, d5 = abp - abc;
    float d2 = acp - aca, d4 = acp - acb, d6 = acp - acc;
    float vc = d1 * d4 - d3 * d2;
    float vb = d5 * d2 - d1 * d6;
    float va = d3 * d6 - d5 * d4;
    float e1 = d4 - d3, e2 = d5 - d6;

    float bpd = apd + abp, cpd = apd + acp;
    float pap = (pp + aa) - 2.0f * apd;
    float pbp = (pp + bb) - 2.0f * bpd;
    float pcp = (pp + cc2) - 2.0f * cpd;
    float nap = npd - na;

    bool ca  = (d1 <= 0.0f) && (d2 <= 0.0f);
    bool cb_ = (d3 >= 0.0f) && (d4 <= d3);
    bool cab = (vc <= 0.0f) && (d1 >= 0.0f) && (d3 <= 0.0f);
    bool cc_ = (d6 >= 0.0f) && (d5 <= d6);
    bool cac = (vb <= 0.0f) && (d2 >= 0.0f) && (d6 <= 0.0f);
    bool cbc = (va <= 0.0f) && (e1 >= 0.0f) && (e2 >= 0.0f);
    bool tk  = ca;
    bool m_b  = cb_ && !tk;  tk = tk || cb_;
    bool m_ab = cab && !tk;  tk = tk || cab;
    bool m_c  = cc_ && !tk;  tk = tk || cc_;
    bool m_ac = cac && !tk;  tk = tk || cac;
    bool m_bc = cbc && !tk;  tk = tk || cbc;
    bool m_in = !tk;

    float base = m_c ? pcp : (m_b || m_bc) ? pbp : pap;
    float num  = m_ab ? d1 : m_ac ? d2 : m_bc ? e1 : nap;
    float inv  = m_ab ? iab : m_ac ? iac : m_bc ? icb : inn;
    bool corr_on = m_ab || m_ac || m_bc || m_in;
    float tcorr = corr_on ? (num * num) * inv : 0.0f;
    return m_in ? tcorr : (base - tcorr);
}

// ---- prep: exact records (AoS) + fast records (COMPONENT-MAJOR) ----
__global__ void k_prep(const int* __restrict__ faces, const float* __restrict__ verts,
                       float* __restrict__ trisA, float4* __restrict__ trisBc, int nF)
{
#pragma clang fp contract(off)
    int i = blockIdx.x * 256 + threadIdx.x;
    if (i >= nF) return;
    int i0 = faces[i * 3 + 0], i1 = faces[i * 3 + 1], i2 = faces[i * 3 + 2];
    float ax = verts[i0 * 3], ay = verts[i0 * 3 + 1], az = verts[i0 * 3 + 2];
    float bx = verts[i1 * 3], by = verts[i1 * 3 + 1], bz = verts[i1 * 3 + 2];
    float cx = verts[i2 * 3], cy = verts[i2 * 3 + 1], cz = verts[i2 * 3 + 2];

    float abx = bx - ax, aby = by - ay, abz = bz - az;
    float acx = cx - ax, acy = cy - ay, acz = cz - az;
    float cbx = cx - bx, cby = cy - by, cbz = cz - bz;

    float* t = &trisA[(size_t)i * RECA];
    t[0]  = ax; t[1]  = ay; t[2]  = az; t[3]  = bx;
    t[4]  = by; t[5]  = bz; t[6]  = cx; t[7]  = cy;
    t[8]  = cz;
    t[9]  = abx; t[10] = aby; t[11] = abz;
    t[12] = acx; t[13] = acy; t[14] = acz;
    t[15] = cbx; t[16] = cby; t[17] = cbz;
    t[18] = 0.0f; t[19] = 0.0f;

    float aba = abx * ax + aby * ay + abz * az;
    float abb = abx * bx + aby * by + abz * bz;
    float abc = abx * cx + aby * cy + abz * cz;
    float aca = acx * ax + acy * ay + acz * az;
    float acb = acx * bx + acy * by + acz * bz;
    float acc = acx * cx + acy * cy + acz * cz;
    float aa = ax * ax + ay * ay + az * az;
    float bb = bx * bx + by * by + bz * bz;
    float ccv = cx * cx + cy * cy + cz * cz;
    float nx = aby * acz - abz * acy;
    float ny = abz * acx - abx * acz;
    float nz = abx * acy - aby * acx;
    float na = nx * ax + ny * ay + nz * az;
    float abab = abx * abx + aby * aby + abz * abz;
    float acac = acx * acx + acy * acy + acz * acz;
    float cbcb = cbx * cbx + cby * cby + cbz * cbz;
    float nn   = nx * nx + ny * ny + nz * nz;

    // component-major: component c of face i at trisBc[c*nF + i]
    trisBc[0 * (size_t)nF + i] = make_float4(abx, aby, abz, acx);
    trisBc[1 * (size_t)nF + i] = make_float4(acy, acz, aba, abb);
    trisBc[2 * (size_t)nF + i] = make_float4(abc, aca, acb, acc);
    trisBc[3 * (size_t)nF + i] = make_float4(aa, bb, ccv, ax);
    trisBc[4 * (size_t)nF + i] = make_float4(ay, az, nx, ny);
    trisBc[5 * (size_t)nF + i] = make_float4(nz, na, 1.0f / safe32(abab), 1.0f / safe32(acac));
    trisBc[6 * (size_t)nF + i] = make_float4(1.0f / safe32(cbcb), 1.0f / safe32(nn), 0.0f, 0.0f);
}

// ---- fused: one LDS pass (m_c[8] minima) + targeted global verify ----
__global__ __launch_bounds__(SQPB) void k_fused(
    const float* __restrict__ trisA, const float4* __restrict__ trisBc,
    const float* __restrict__ query, float* __restrict__ out, int nF, int nQ)
{
    __shared__ float4 sB[7][CHUNK];
    const int tid = threadIdx.x;
    const int lane = tid & 63;
    const int q = blockIdx.x * (SQPB / 64) + (tid >> 6);
    const bool valid = q < nQ;

    float px = 0.f, py = 0.f, pz = 0.f, pp = 0.f;
    if (valid) {
        px = query[q * 3]; py = query[q * 3 + 1]; pz = query[q * 3 + 2];
        pp = px * px + py * py + pz * pz;
    }

    float best = 3.402823466e38f;
    int bidx = 0x7fffffff;

    for (int sc = 0; sc < nF; sc += SUPER) {
        float m_c[NCH];
#pragma unroll
        for (int c = 0; c < NCH; ++c) m_c[c] = 3.402823466e38f;

        // ---- single LDS pass: per-chunk approx minima ----
#pragma unroll
        for (int c = 0; c < NCH; ++c) {
            const int fbase = sc + c * CHUNK;
            if (fbase < nF) {
                const int cnt = min(CHUNK, nF - fbase);
                __syncthreads();
                for (int i = tid; i < CHUNK * 7; i += SQPB) {
                    int comp = i >> 8, f = i & (CHUNK - 1);
                    if (f < cnt)
                        sB[comp][f] = trisBc[(size_t)comp * nF + fbase + f];
                }
                __syncthreads();
                if (valid) {
#pragma unroll
                    for (int it = 0; it < CHUNK / 64; ++it) {
                        int j = it * 64 + lane;
                        if (j < cnt) {
                            float d2a = d2approx(px, py, pz, pp,
                                sB[0][j], sB[1][j], sB[2][j], sB[3][j],
                                sB[4][j], sB[5][j], sB[6][j]);
                            m_c[c] = fminf(m_c[c], d2a);
                        }
                    }
                }
            }
        }

        // m1 = min over chunks, then wave-reduce (uniform across wave)
        float m1 = 3.402823466e38f;
#pragma unroll
        for (int c = 0; c < NCH; ++c) m1 = fminf(m1, m_c[c]);
        for (int o = 32; o > 0; o >>= 1) m1 = fminf(m1, __shfl_xor(m1, o));
        // |d2a - d2exact| <= E ~ 7e-5; margin >= 4E (verified R9 certificate):
        // candidate set {f : d2a <= m1+margin} contains every exact-minimal
        // face incl. all ties; excluded faces strictly larger exact d2.
        const float thresh = m1 + (3e-4f + 1e-4f * m1);

        // ---- verify: only flagged chunks, coalesced L2 reads, masked cp32 ----
        if (valid) {
#pragma unroll
            for (int c = 0; c < NCH; ++c) {
                const int fbase = sc + c * CHUNK;
                if (fbase < nF && __any(m_c[c] <= thresh)) {
                    const int cnt = min(CHUNK, nF - fbase);
#pragma unroll
                    for (int it = 0; it < CHUNK / 64; ++it) {
                        int j = it * 64 + lane;
                        if (j < cnt) {
                            int f = fbase + j;
                            float4 r0 = trisBc[0 * (size_t)nF + f];
                            float4 r1 = trisBc[1 * (size_t)nF + f];
                            float4 r2 = trisBc[2 * (size_t)nF + f];
                            float4 r3 = trisBc[3 * (size_t)nF + f];
                            float4 r4 = trisBc[4 * (size_t)nF + f];
                            float4 r5 = trisBc[5 * (size_t)nF + f];
                            float4 r6 = trisBc[6 * (size_t)nF + f];
                            float d2a = d2approx(px, py, pz, pp,
                                                 r0, r1, r2, r3, r4, r5, r6);
                            if (d2a <= thresh) {
                                float rx, ry, rz;
                                float d2 = cp32(px, py, pz,
                                    &trisA[(size_t)f * RECA], rx, ry, rz);
                                // ascending f per lane: first occurrence
                                if (d2 < best) { best = d2; bidx = f; }
                            }
                        }
                    }
                }
            }
        }
    }

    // verified lexicographic (d2, idx) wave reduction
    for (int o = 32; o > 0; o >>= 1) {
        float od = __shfl_down(best, o);
        int   oi = __shfl_down(bidx, o);
        if (od < best || (od == best && oi < bidx)) { best = od; bidx = oi; }
    }
    if (valid && lane == 0) write_result(q, bidx, trisA, px, py, pz, out);
}

extern "C" void kernel_launch(void* const* d_in, const int* in_sizes, int n_in,
                              void* d_out, int out_size, void* d_ws, size_t ws_size,
                              hipStream_t stream) {
    const int* faces = (const int*)d_in[0];
    const float* verts = (const float*)d_in[1];
    const float* query = (const float*)d_in[2];
    float* out = (float*)d_out;

    const int nF = in_sizes[0] / 3;
    const int nQ = in_sizes[2] / 3;

    char* ws = (char*)d_ws;
    float* trisA = (float*)ws;                                   // nF*20 f32
    float4* trisBc = (float4*)(ws + (size_t)nF * RECA * 4);      // nF*7 float4

    k_prep<<<(nF + 255) / 256, 256, 0, stream>>>(faces, verts, trisA, trisBc, nF);

    int blocks = (nQ + (SQPB / 64) - 1) / (SQPB / 64);
    k_fused<<<blocks, SQPB, 0, stream>>>(trisA, trisBc, query, out, nF, nQ);
}

// Round 11
// 141.433 us; speedup vs baseline: 1.2645x; 1.2645x over previous
//
#include <hip/hip_runtime.h>
#include <stdint.h>

// SDF closest-point + signed distance, 8192 queries x 2048 tris.
//
// Verified correctness model (R4-R10): harness ref = numpy float32 faithful
// chain; strict IEEE f32, NO fma contraction (pragma inside function), numpy
// op order, np.argmin first-occurrence. cp32/write_result verified. u64
// atomicMin on (exact d2 bits<<32 | idx) == lexicographic (d2, idx) min ==
// np.argmin first occurrence (verified R5). Candidate-set margin certificate
// verified R9/R10.
//
// R11 structure: R6's proven no-LDS scalar-broadcast decomposition (query-
// per-thread x 32-face chunks; face records wave-uniform -> s_load -> SGPRs;
// no barriers; 2048 blocks) applied to BOTH phases of filter-then-verify:
//   A: clamped approx d2 -> u32 atomicMin (float-bit monotone) per query.
//   B: recompute approx; candidates (d2a <= m1+margin, margin >= 2E even
//      without bitwise A/B repro) get exact cp32 -> u64 atomicMin key.
//   C: write_result from winning key.

#define RECA 20   // exact record: a,b,c,ab,ac,cb,pad2
#define RECB 28   // fast record: ab,ac,6dots,aa,bb,cc,a,n,na,4invs,pad2
#define FCA 32    // faces per chunk (block.y)
#define QPB 256   // queries per block

__device__ __forceinline__ float safe32(float x) {
    return (fabsf(x) < 1e-12f) ? 1e-12f : x;
}

// ---- exact path (verified bit-exact vs np-f32 in R4..R10) ----
__device__ __forceinline__ float cp32(
    float px, float py, float pz, const float* __restrict__ t,
    float& rx, float& ry, float& rz)
{
#pragma clang fp contract(off)
    float ax  = t[0],  ay  = t[1],  az  = t[2];
    float bx  = t[3],  by  = t[4],  bz  = t[5];
    float cx  = t[6],  cy  = t[7],  cz  = t[8];
    float abx = t[9],  aby = t[10], abz = t[11];
    float acx = t[12], acy = t[13], acz = t[14];
    float cbx = t[15], cby = t[16], cbz = t[17];

    float apx = px - ax, apy = py - ay, apz = pz - az;
    float bpx = px - bx, bpy = py - by, bpz = pz - bz;
    float qpx = px - cx, qpy = py - cy, qpz = pz - cz;

    float d1 = ((abx * apx) + (aby * apy)) + (abz * apz);
    float d2 = ((acx * apx) + (acy * apy)) + (acz * apz);
    float d3 = ((abx * bpx) + (aby * bpy)) + (abz * bpz);
    float d4 = ((acx * bpx) + (acy * bpy)) + (acz * bpz);
    float d5 = ((abx * qpx) + (aby * qpy)) + (abz * qpz);
    float d6 = ((acx * qpx) + (acy * qpy)) + (acz * qpz);

    float vc = (d1 * d4) - (d3 * d2);
    float vb = (d5 * d2) - (d1 * d6);
    float va = (d3 * d6) - (d5 * d4);
    float e1 = d4 - d3;
    float e2 = d5 - d6;

    bool ca  = (d1 <= 0.0f) && (d2 <= 0.0f);
    bool cb_ = (d3 >= 0.0f) && (d4 <= d3);
    bool cab = (vc <= 0.0f) && (d1 >= 0.0f) && (d3 <= 0.0f);
    bool cc_ = (d6 >= 0.0f) && (d5 <= d6);
    bool cac = (vb <= 0.0f) && (d2 >= 0.0f) && (d6 <= 0.0f);
    bool cbc = (va <= 0.0f) && (e1 >= 0.0f) && (e2 >= 0.0f);

    bool tk  = ca;
    bool m_b  = cb_ && !tk;  tk = tk || cb_;
    bool m_ab = cab && !tk;  tk = tk || cab;
    bool m_c  = cc_ && !tk;  tk = tk || cc_;
    bool m_ac = cac && !tk;  tk = tk || cac;
    bool m_bc = cbc && !tk;  tk = tk || cbc;
    bool m_in = !tk;

    float denom_raw = (va + vb) + vc;
    float num1 = m_ab ? d1 : m_ac ? d2 : m_bc ? e1 : m_in ? vb : 0.0f;
    float den1_raw = m_ab ? (d1 - d3) : m_ac ? (d2 - d6)
                   : m_bc ? (e1 + e2) : m_in ? denom_raw : 1.0f;
    float den1  = safe32(den1_raw);
    float denom = safe32(denom_raw);
    float num2  = m_in ? vc : 0.0f;
    float q1 = num1 / den1;
    float q2 = num2 / denom;

    bool sel_b = m_b || m_bc;
    float basx = m_c ? cx : sel_b ? bx : ax;
    float basy = m_c ? cy : sel_b ? by : ay;
    float basz = m_c ? cz : sel_b ? bz : az;

    bool s_ab = m_ab || m_in;
    float t1x = m_bc ? cbx : m_ac ? acx : s_ab ? abx : 0.0f;
    float t1y = m_bc ? cby : m_ac ? acy : s_ab ? aby : 0.0f;
    float t1z = m_bc ? cbz : m_ac ? acz : s_ab ? abz : 0.0f;

    float t2x = m_in ? acx : 0.0f;
    float t2y = m_in ? acy : 0.0f;
    float t2z = m_in ? acz : 0.0f;

    rx = (basx + (t1x * q1)) + (t2x * q2);
    ry = (basy + (t1y * q1)) + (t2y * q2);
    rz = (basz + (t1z * q1)) + (t2z * q2);

    float dx = px - rx, dy = py - ry, dz = pz - rz;
    return ((dx * dx) + (dy * dy)) + (dz * dz);
}

// Exact epilogue (verified): recompute winner, normal, sign, write.
__device__ __forceinline__ void write_result(
    int q, int widx, const float* __restrict__ trisA,
    float px, float py, float pz, float* __restrict__ out)
{
#pragma clang fp contract(off)
    const float* t = &trisA[(size_t)widx * RECA];
    float rx, ry, rz;
    float best_d2 = cp32(px, py, pz, t, rx, ry, rz);

    float abx = t[9],  aby = t[10], abz = t[11];
    float acx = t[12], acy = t[13], acz = t[14];
    float nx = (aby * acz) - (abz * acy);
    float ny = (abz * acx) - (abx * acz);
    float nz = (abx * acy) - (aby * acx);

    float dx = px - rx, dy = py - ry, dz = pz - rz;
    float sdot = ((dx * nx) + (dy * ny)) + (dz * nz);
    float sgn = (sdot >= 0.0f) ? 1.0f : -1.0f;
    float sdist = sgn * __fsqrt_rn(fmaxf(best_d2, 0.0f));

    out[q * 4 + 0] = rx;
    out[q * 4 + 1] = ry;
    out[q * 4 + 2] = rz;
    out[q * 4 + 3] = sdist;
}

// Fast approximate d2, clamped to >= 0 (two-sided abs error E ~ 7e-5;
// clamping only moves d2a toward the exact nonneg value). FMA allowed.
// Record t[0..27]: abx,aby,abz,acx,acy,acz,aba,abb,abc,aca,acb,acc,
//                  aa,bb,cc,ax,ay,az,nx,ny,nz,na,iab,iac,icb,inn,pad,pad
__device__ __forceinline__ float d2approx(
    float px, float py, float pz, float pp, const float* __restrict__ t)
{
    float abx = t[0],  aby = t[1],  abz = t[2];
    float acx = t[3],  acy = t[4],  acz = t[5];
    float aba = t[6],  abb = t[7],  abc = t[8];
    float aca = t[9],  acb = t[10], acc = t[11];
    float aa  = t[12], bb  = t[13], cc2 = t[14];
    float ax  = t[15], ay  = t[16], az  = t[17];
    float nx  = t[18], ny  = t[19], nz  = t[20];
    float na  = t[21], iab = t[22], iac = t[23];
    float icb = t[24], inn = t[25];

    float abp = abx * px + aby * py + abz * pz;
    float acp = acx * px + acy * py + acz * pz;
    float apd = ax * px + ay * py + az * pz;
    float npd = nx * px + ny * py + nz * pz;
    float d1 = abp - aba, d3 = abp - abb, d5 = abp - abc;
    float d2 = acp - aca, d4 = acp - acb, d6 = acp - acc;
    float vc = d1 * d4 - d3 * d2;
    float vb = d5 * d2 - d1 * d6;
    float va = d3 * d6 - d5 * d4;
    float e1 = d4 - d3, e2 = d5 - d6;

    float bpd = apd + abp, cpd = apd + acp;
    float pap = (pp + aa) - 2.0f * apd;
    float pbp = (pp + bb) - 2.0f * bpd;
    float pcp = (pp + cc2) - 2.0f * cpd;
    float nap = npd - na;

    bool ca  = (d1 <= 0.0f) && (d2 <= 0.0f);
    bool cb_ = (d3 >= 0.0f) && (d4 <= d3);
    bool cab = (vc <= 0.0f) && (d1 >= 0.0f) && (d3 <= 0.0f);
    bool cc_ = (d6 >= 0.0f) && (d5 <= d6);
    bool cac = (vb <= 0.0f) && (d2 >= 0.0f) && (d6 <= 0.0f);
    bool cbc = (va <= 0.0f) && (e1 >= 0.0f) && (e2 >= 0.0f);
    bool tk  = ca;
    bool m_b  = cb_ && !tk;  tk = tk || cb_;
    bool m_ab = cab && !tk;  tk = tk || cab;
    bool m_c  = cc_ && !tk;  tk = tk || cc_;
    bool m_ac = cac && !tk;  tk = tk || cac;
    bool m_bc = cbc && !tk;  tk = tk || cbc;
    bool m_in = !tk;

    float base = m_c ? pcp : (m_b || m_bc) ? pbp : pap;
    float num  = m_ab ? d1 : m_ac ? d2 : m_bc ? e1 : nap;
    float inv  = m_ab ? iab : m_ac ? iac : m_bc ? icb : inn;
    bool corr_on = m_ab || m_ac || m_bc || m_in;
    float tcorr = corr_on ? (num * num) * inv : 0.0f;
    float v = m_in ? tcorr : (base - tcorr);
    return fmaxf(v, 0.0f);   // clamp: required for u32 float-bit atomicMin
}

// ---- prep: exact + fast records (AoS), init both key arrays ----
__global__ void k_prep(const int* __restrict__ faces, const float* __restrict__ verts,
                       float* __restrict__ trisA, float* __restrict__ trisB,
                       unsigned* __restrict__ keyA, unsigned long long* __restrict__ keyB,
                       int nF, int nQ)
{
#pragma clang fp contract(off)
    int i = blockIdx.x * 256 + threadIdx.x;
    if (i < nQ) { keyA[i] = 0xffffffffu; keyB[i] = 0xffffffffffffffffULL; }
    if (i >= nF) return;
    int i0 = faces[i * 3 + 0], i1 = faces[i * 3 + 1], i2 = faces[i * 3 + 2];
    float ax = verts[i0 * 3], ay = verts[i0 * 3 + 1], az = verts[i0 * 3 + 2];
    float bx = verts[i1 * 3], by = verts[i1 * 3 + 1], bz = verts[i1 * 3 + 2];
    float cx = verts[i2 * 3], cy = verts[i2 * 3 + 1], cz = verts[i2 * 3 + 2];

    float abx = bx - ax, aby = by - ay, abz = bz - az;
    float acx = cx - ax, acy = cy - ay, acz = cz - az;
    float cbx = cx - bx, cby = cy - by, cbz = cz - bz;

    float* t = &trisA[(size_t)i * RECA];
    t[0]  = ax; t[1]  = ay; t[2]  = az; t[3]  = bx;
    t[4]  = by; t[5]  = bz; t[6]  = cx; t[7]  = cy;
    t[8]  = cz;
    t[9]  = abx; t[10] = aby; t[11] = abz;
    t[12] = acx; t[13] = acy; t[14] = acz;
    t[15] = cbx; t[16] = cby; t[17] = cbz;
    t[18] = 0.0f; t[19] = 0.0f;

    float aba = abx * ax + aby * ay + abz * az;
    float abb = abx * bx + aby * by + abz * bz;
    float abc = abx * cx + aby * cy + abz * cz;
    float aca = acx * ax + acy * ay + acz * az;
    float acb = acx * bx + acy * by + acz * bz;
    float acc = acx * cx + acy * cy + acz * cz;
    float aa = ax * ax + ay * ay + az * az;
    float bb = bx * bx + by * by + bz * bz;
    float ccv = cx * cx + cy * cy + cz * cz;
    float nx = aby * acz - abz * acy;
    float ny = abz * acx - abx * acz;
    float nz = abx * acy - aby * acx;
    float na = nx * ax + ny * ay + nz * az;
    float abab = abx * abx + aby * aby + abz * abz;
    float acac = acx * acx + acy * acy + acz * acz;
    float cbcb = cbx * cbx + cby * cby + cbz * cbz;
    float nn   = nx * nx + ny * ny + nz * nz;

    float* u = &trisB[(size_t)i * RECB];
    u[0]  = abx; u[1]  = aby; u[2]  = abz;
    u[3]  = acx; u[4]  = acy; u[5]  = acz;
    u[6]  = aba; u[7]  = abb; u[8]  = abc;
    u[9]  = aca; u[10] = acb; u[11] = acc;
    u[12] = aa;  u[13] = bb;  u[14] = ccv;
    u[15] = ax;  u[16] = ay;  u[17] = az;
    u[18] = nx;  u[19] = ny;  u[20] = nz;
    u[21] = na;
    u[22] = 1.0f / safe32(abab);
    u[23] = 1.0f / safe32(acac);
    u[24] = 1.0f / safe32(cbcb);
    u[25] = 1.0f / safe32(nn);
    u[26] = 0.0f; u[27] = 0.0f;
}

// ---- A: approx scan. thread=query, block.y=32-face chunk, faces in SGPRs.
// u32 atomicMin on clamped d2a float bits (monotone for >=0).
__global__ __launch_bounds__(QPB) void k_scanA(
    const float* __restrict__ trisB, const float* __restrict__ query,
    unsigned* __restrict__ keyA, int nF, int nQ)
{
    const int fbase = blockIdx.y * FCA;
    const int nf = min(FCA, nF - fbase);
    const int q = blockIdx.x * QPB + threadIdx.x;
    if (q >= nQ) return;
    const float px = query[q * 3], py = query[q * 3 + 1], pz = query[q * 3 + 2];
    const float pp = px * px + py * py + pz * pz;

    float m1 = 3.402823466e38f;
#pragma unroll 2
    for (int f = 0; f < nf; ++f)
        m1 = fminf(m1, d2approx(px, py, pz, pp, &trisB[(size_t)(fbase + f) * RECB]));

    atomicMin(&keyA[q], __float_as_uint(m1));
}

// ---- B: verify. Same shape; candidates get exact cp32 + u64 key. ----
__global__ __launch_bounds__(QPB) void k_scanB(
    const float* __restrict__ trisA, const float* __restrict__ trisB,
    const float* __restrict__ query, const unsigned* __restrict__ keyA,
    unsigned long long* __restrict__ keyB, int nF, int nQ)
{
    const int fbase = blockIdx.y * FCA;
    const int nf = min(FCA, nF - fbase);
    const int q = blockIdx.x * QPB + threadIdx.x;
    if (q >= nQ) return;
    const float px = query[q * 3], py = query[q * 3 + 1], pz = query[q * 3 + 2];
    const float pp = px * px + py * py + pz * pz;

    // m1 within E of exact min; margin >= 2E: every exact-minimal face f*
    // has d2a(f*) <= d2exact(f*) + E <= (m1 + E) + E <= thresh. Certified
    // candidate set; excluded faces strictly larger exact d2 (R9/R10).
    const float m1 = __uint_as_float(keyA[q]);
    const float thresh = m1 + (3e-4f + 1e-4f * m1);

    unsigned long long bestkey = 0xffffffffffffffffULL;
#pragma unroll 2
    for (int f = 0; f < nf; ++f) {
        float d2a = d2approx(px, py, pz, pp, &trisB[(size_t)(fbase + f) * RECB]);
        if (d2a <= thresh) {
            float rx, ry, rz;
            float d2 = cp32(px, py, pz, &trisA[(size_t)(fbase + f) * RECA],
                            rx, ry, rz);
            unsigned long long k =
                ((unsigned long long)__float_as_uint(d2) << 32)
                | (unsigned)(fbase + f);
            bestkey = (k < bestkey) ? k : bestkey;
        }
    }
    if (bestkey != 0xffffffffffffffffULL) atomicMin(&keyB[q], bestkey);
}

// ---- C: finalize winner (verified write_result) ----
__global__ void k_finalC(const float* __restrict__ trisA,
                         const float* __restrict__ query,
                         const unsigned long long* __restrict__ keyB,
                         float* __restrict__ out, int nQ)
{
    int q = blockIdx.x * 256 + threadIdx.x;
    if (q >= nQ) return;
    int idx = (int)(keyB[q] & 0xffffffffULL);
    const float px = query[q * 3], py = query[q * 3 + 1], pz = query[q * 3 + 2];
    write_result(q, idx, trisA, px, py, pz, out);
}

extern "C" void kernel_launch(void* const* d_in, const int* in_sizes, int n_in,
                              void* d_out, int out_size, void* d_ws, size_t ws_size,
                              hipStream_t stream) {
    const int* faces = (const int*)d_in[0];
    const float* verts = (const float*)d_in[1];
    const float* query = (const float*)d_in[2];
    float* out = (float*)d_out;

    const int nF = in_sizes[0] / 3;
    const int nQ = in_sizes[2] / 3;

    char* ws = (char*)d_ws;
    unsigned long long* keyB = (unsigned long long*)ws;            // nQ u64
    unsigned* keyA = (unsigned*)(ws + (size_t)nQ * 8);             // nQ u32
    float* trisA = (float*)(ws + (size_t)nQ * 12);                 // nF*20 f32
    float* trisB = trisA + (size_t)nF * RECA;                      // nF*28 f32

    int prep_threads = (nQ > nF ? nQ : nF);
    k_prep<<<(prep_threads + 255) / 256, 256, 0, stream>>>(
        faces, verts, trisA, trisB, keyA, keyB, nF, nQ);

    dim3 grid((nQ + QPB - 1) / QPB, (nF + FCA - 1) / FCA);
    k_scanA<<<grid, QPB, 0, stream>>>(trisB, query, keyA, nF, nQ);
    k_scanB<<<grid, QPB, 0, stream>>>(trisA, trisB, query, keyA, keyB, nF, nQ);

    k_finalC<<<(nQ + 255) / 256, 256, 0, stream>>>(trisA, query, keyB, out, nQ);
}